// Round 22
// baseline (31.917 us; speedup 1.0000x reference)
//
#include <hip/hip_runtime.h>

#define N_RAYS     131072
#define MAX_STEPS  128
#define R2_CULL    0.65f     // sigma line-integral outside <= 7.4e-4 (verified R16)

// Identity barrier: forces the value through a VGPR via empty inline asm.
__device__ __forceinline__ float opq(float x) { asm("" : "+v"(x)); return x; }

__global__ __launch_bounds__(256, 8) void renderer_kernel(
    const float* __restrict__ raysO,
    const float* __restrict__ raysD,
    const float* __restrict__ grid,
    float* __restrict__ out)
{
    #pragma clang fp contract(off)

    const int tid  = blockIdx.x * blockDim.x + threadIdx.x;
    const int r    = tid >> 4;         // ray index (4 rays per wave)
    const int lane16 = tid & 15;       // step-lane within the ray group
    if (r >= N_RAYS) return;

    const float ox = raysO[3*r+0], oy = raysO[3*r+1], oz = raysO[3*r+2];
    const float dx = raysD[3*r+0], dy = raysD[3*r+1], dz = raysD[3*r+2];

    // ---- slab: strict f32, recip-mult form (verified R12/R18) ----
    const float sdx = (fabsf(dx) > 1e-8f) ? dx : 1e-8f;
    const float sdy = (fabsf(dy) > 1e-8f) ? dy : 1e-8f;
    const float sdz = (fabsf(dz) > 1e-8f) ? dz : 1e-8f;
    const float rdx = opq(1.0f / sdx);
    const float rdy = opq(1.0f / sdy);
    const float rdz = opq(1.0f / sdz);
    const float t0x = opq(opq(-2.0f - ox) * rdx);
    const float t1x = opq(opq( 2.0f - ox) * rdx);
    const float t0y = opq(opq(-2.0f - oy) * rdy);
    const float t1y = opq(opq( 2.0f - oy) * rdy);
    const float t0z = opq(opq(-2.0f - oz) * rdz);
    const float t1z = opq(opq( 2.0f - oz) * rdz);
    const float tmin = fmaxf(fmaxf(fminf(t0x, t1x), fminf(t0y, t1y)), fminf(t0z, t1z));
    const float tmax = fminf(fminf(fmaxf(t0x, t1x), fmaxf(t0y, t1y)), fmaxf(t0z, t1z));
    const float nearT = fmaxf(tmin, 0.05f);
    const float farT  = fmaxf(tmax, opq(nearT + 1e-6f));
    const float dtv   = opq(opq(farT - nearT) * 0.0078125f);   // /128: pow2-exact

    // ---- blob culling (verified R13/R16) ----
    int s_lo = 0, s_hi = -1;
    {
        const float b    = ox*dx + oy*dy + oz*dz;
        const float c    = ox*ox + oy*oy + oz*oz - R2_CULL;
        const float disc = b*b - c;
        if (disc > 0.0f) {
            const float sq = sqrtf(disc) + 0.01f;
            const float inv_dt = 1.0f / dtv;
            float fs_lo = (-b - sq - nearT) * inv_dt - 0.5f;
            float fs_hi = (-b + sq - nearT) * inv_dt - 0.5f;
            fs_lo = fminf(fmaxf(fs_lo, -2.0f), 130.0f);
            fs_hi = fminf(fmaxf(fs_hi, -2.0f), 130.0f);
            s_lo = max(0, (int)floorf(fs_lo) - 1);
            s_hi = min(MAX_STEPS - 1, (int)ceilf(fs_hi) + 1);
        }
    }

    // Running composition for this ray (uniform across the 16-lane group).
    float Trun = 1.0f;
    float accR = 0.0f, accG = 0.0f, accB = 0.0f;
    float wsum = 0.0f;

    const float INV_2R2 = 1.0f / 0.08f;

    // ---- strides of 16 consecutive steps; lane k handles step base+k ----
    for (int base = s_lo; base <= s_hi; base += 16) {
        const int  s_raw = base + lane16;
        const bool valid = (s_raw <= s_hi);
        const int  s     = min(s_raw, s_hi);                   // clamp: stays in window

        // ---- verified per-step DECISION chain (bit-identical to R12) ----
        const float sp = opq((float)s + 0.5f);                 // exact
        const float t  = opq(__builtin_fmaf(sp, dtv, nearT));  // fused
        const float x  = opq(ox + opq(t * dx));                // strict
        const float y  = opq(oy + opq(t * dy));
        const float z  = opq(oz + opq(t * dz));

        const float ux = opq(opq(x * 0.5f) + 0.5f);            // cas=0 proven
        const float uy = opq(opq(y * 0.5f) + 0.5f);
        const float uz = opq(opq(z * 0.5f) + 0.5f);
        const int ixv = (int)opq(ux * 128.0f);                 // pow2-exact
        const int iyv = (int)opq(uy * 128.0f);
        const int izv = (int)opq(uz * 128.0f);

        const float gv = grid[(ixv << 14) + (iyv << 7) + izv]; // adjacent-lane local
        const bool occ = valid && (gv > 10.0f);                // exact compare

        // ---- single-step segment values (invalid lanes = exact identity) ----
        const float d2     = __builtin_fmaf(x, x, __builtin_fmaf(y, y, z * z));
        const float sigma0 = 5.0f * __expf(-(d2 * INV_2R2));
        const float sigma  = occ ? sigma0 : 0.0f;
        const float alpha  = 1.0f - __expf(-(sigma * dtv));    // occ=0 -> alpha=0

        float Tl  = 1.0f - alpha;                              // segment T
        float aRl = alpha * __builtin_fmaf(x, 0.25f, 0.5f);    // segment acc
        float aGl = alpha * __builtin_fmaf(y, 0.25f, 0.5f);
        float aBl = alpha * __builtin_fmaf(z, 0.25f, 0.5f);
        float wl  = alpha;

        // ---- ordered associative butterfly over the 16-lane group ----
        const int lane = threadIdx.x & 63;
        #pragma unroll
        for (int m = 1; m <= 8; m <<= 1) {
            const float To  = __shfl_xor(Tl,  m);
            const float aRo = __shfl_xor(aRl, m);
            const float aGo = __shfl_xor(aGl, m);
            const float aBo = __shfl_xor(aBl, m);
            const float wo  = __shfl_xor(wl,  m);
            const bool left = ((lane & m) == 0);
            const float Tf  = left ? Tl  : To;
            const float aR1 = left ? aRl : aRo, aR2 = left ? aRo : aRl;
            const float aG1 = left ? aGl : aGo, aG2 = left ? aGo : aGl;
            const float aB1 = left ? aBl : aBo, aB2 = left ? aBo : aBl;
            const float w1  = left ? wl  : wo,  w2  = left ? wo  : wl;
            aRl = aR1 + Tf * aR2;
            aGl = aG1 + Tf * aG2;
            aBl = aB1 + Tf * aB2;
            wl  = w1  + Tf * w2;
            Tl  = Tl * To;
        }

        // ---- chain this stride after the running composition ----
        accR = accR + Trun * aRl;
        accG = accG + Trun * aGl;
        accB = accB + Trun * aBl;
        wsum = wsum + Trun * wl;
        Trun = Trun * Tl;
    }

    if (lane16 == 0) {
        const float bg = 1.0f - wsum;   // bgColor = 1
        out[3*r+0] = accR + bg;
        out[3*r+1] = accG + bg;
        out[3*r+2] = accB + bg;
    }
}

extern "C" void kernel_launch(void* const* d_in, const int* in_sizes, int n_in,
                              void* d_out, int out_size, void* d_ws, size_t ws_size,
                              hipStream_t stream) {
    const float* raysO = (const float*)d_in[0];
    const float* raysD = (const float*)d_in[1];
    const float* grid  = (const float*)d_in[2];
    float* out = (float*)d_out;

    const int threads = 256;
    const long long total = (long long)N_RAYS * 16;      // 16 step-lanes per ray
    const int blocks  = (int)((total + threads - 1) / threads); // 8192
    renderer_kernel<<<blocks, threads, 0, stream>>>(raysO, raysD, grid, out);
}